// Round 12
// baseline (591.707 us; speedup 1.0000x reference)
//
#include <hip/hip_runtime.h>
#include <math.h>

#define T_TRI 20000
#define KNN_K 20
#define H     128
#define GRES  32
#define NCELL (GRES*GRES*GRES)

// ---------------- workspace layout (bytes) ----------------
#define WS_GEO    0                       // 960KB (original-space geo, copied to geo_s)
#define WS_BQ     (1u<<20)                // 320KB
#define WS_NBR    (2u<<20)                // 1.6MB (sorted-space neighbor lists)
#define WS_RS     (4u<<20)                // 512B
#define WS_WT     ((4u<<20)+4096)         // 320KB
#define WS_MM     (5u<<20)                // 64B
#define WS_HIST   ((5u<<20)+(4u<<10))    // 128KB
#define WS_CSTART ((5u<<20)+(256u<<10))  // 128KB+8
#define WS_CPTR   ((5u<<20)+(512u<<10))  // 128KB
#define WS_CID    ((5u<<20)+(768u<<10))  // 80KB
#define WS_CSORT  ((5u<<20)+(896u<<10))  // 80KB
#define WS_OID    (6u<<20)               // 80KB
#define WS_BQS    ((6u<<20)+(128u<<10))  // 320KB
#define WS_PS     ((6u<<20)+(512u<<10))  // 80KB (probs_s)
#define WS_GEOS   (7u<<20)               // 960KB (sorted-space geo)
#define WS_X      (9u<<20)
#define WS_Y      (20u<<20)

__device__ __forceinline__ float readlane_f(float v, int l) {
    return __uint_as_float(__builtin_amdgcn_readlane(__float_as_uint(v), l));
}
// order-preserving float<->uint (for atomicMin/Max on floats)
__device__ __forceinline__ unsigned encf(float f) {
    unsigned u = __float_as_uint(f);
    return (u & 0x80000000u) ? ~u : (u | 0x80000000u);
}
__device__ __forceinline__ float decf(unsigned e) {
    unsigned u = (e & 0x80000000u) ? (e & 0x7FFFFFFFu) : ~e;
    return __uint_as_float(u);
}

// ---------------- init: zero histogram, minmax sentinels ----------------
__global__ void grid_init_kernel(unsigned* __restrict__ hist, unsigned* __restrict__ mm) {
    int i = blockIdx.x * 256 + threadIdx.x;
    if (i < NCELL) hist[i] = 0u;
    if (i < 3) mm[i] = 0xFFFFFFFFu;          // mins (uint-encoded)
    if (i >= 3 && i < 6) mm[i] = 0u;         // maxs
}

// ---------------- geometry (+ bary AABB via wave-reduced atomics) ----------------
__global__ void geom_kernel(const float* __restrict__ pts, const int* __restrict__ tris,
                            float* __restrict__ geo, float4* __restrict__ bq,
                            unsigned* __restrict__ mm) {
    int t = blockIdx.x * blockDim.x + threadIdx.x;
    int lane = threadIdx.x & 63;
    bool act = (t < T_TRI);
    int tt = act ? t : 0;
    int i0 = tris[3*tt], i1 = tris[3*tt+1], i2 = tris[3*tt+2];
    float ax = pts[3*i0], ay = pts[3*i0+1], az = pts[3*i0+2];
    float bx = pts[3*i1], by = pts[3*i1+1], bz = pts[3*i1+2];
    float cx = pts[3*i2], cy = pts[3*i2+1], cz = pts[3*i2+2];
    float e0x = ax-bx, e0y = ay-by, e0z = az-bz;   // e_ij
    float e1x = ax-cx, e1y = ay-cy, e1z = az-cz;   // e_ik
    float e2x = bx-cx, e2y = by-cy, e2z = bz-cz;   // e_jk
    float mnx = fminf(fminf(e0x,e1x),e2x), mny = fminf(fminf(e0y,e1y),e2y), mnz = fminf(fminf(e0z,e1z),e2z);
    float mxx = fmaxf(fmaxf(e0x,e1x),e2x), mxy = fmaxf(fmaxf(e0y,e1y),e2y), mxz = fmaxf(fmaxf(e0z,e1z),e2z);
    float gx = (ax+bx+cx)*(1.0f/3.0f), gy = (ay+by+cy)*(1.0f/3.0f), gz = (az+bz+cz)*(1.0f/3.0f);
    float sq = (gx*gx + gy*gy) + gz*gz;
    if (act) {
        float* g = geo + (size_t)t*12;
        g[0]=mnx; g[1]=mny; g[2]=mnz; g[3]=mxx; g[4]=mxy; g[5]=mxz;
        g[6]=gx;  g[7]=gy;  g[8]=gz;  g[9]=0.f; g[10]=0.f; g[11]=0.f;
        bq[t] = make_float4(gx, gy, gz, sq);
    }
    unsigned n0 = act ? encf(gx) : 0xFFFFFFFFu;
    unsigned n1 = act ? encf(gy) : 0xFFFFFFFFu;
    unsigned n2 = act ? encf(gz) : 0xFFFFFFFFu;
    unsigned x0 = act ? encf(gx) : 0u;
    unsigned x1 = act ? encf(gy) : 0u;
    unsigned x2 = act ? encf(gz) : 0u;
#pragma unroll
    for (int off = 32; off >= 1; off >>= 1) {
        n0 = min(n0, (unsigned)__shfl_xor((int)n0, off));
        n1 = min(n1, (unsigned)__shfl_xor((int)n1, off));
        n2 = min(n2, (unsigned)__shfl_xor((int)n2, off));
        x0 = max(x0, (unsigned)__shfl_xor((int)x0, off));
        x1 = max(x1, (unsigned)__shfl_xor((int)x1, off));
        x2 = max(x2, (unsigned)__shfl_xor((int)x2, off));
    }
    if (lane == 0) {
        atomicMin(&mm[0], n0); atomicMin(&mm[1], n1); atomicMin(&mm[2], n2);
        atomicMax(&mm[3], x0); atomicMax(&mm[4], x1); atomicMax(&mm[5], x2);
    }
}

// ---------------- cell assignment + histogram (32^3) ----------------
__global__ void cellhist_kernel(const float4* __restrict__ bq, const unsigned* __restrict__ mm,
                                int* __restrict__ cellid, unsigned* __restrict__ hist) {
    int t = blockIdx.x * 256 + threadIdx.x;
    if (t >= T_TRI) return;
    float mnx = decf(mm[0]), mny = decf(mm[1]), mnz = decf(mm[2]);
    float mxx = decf(mm[3]), mxy = decf(mm[4]), mxz = decf(mm[5]);
    float ihx = (float)GRES / fmaxf(mxx-mnx, 1e-30f);
    float ihy = (float)GRES / fmaxf(mxy-mny, 1e-30f);
    float ihz = (float)GRES / fmaxf(mxz-mnz, 1e-30f);
    float4 b = bq[t];
    int ix = min(GRES-1, max(0, (int)((b.x-mnx)*ihx)));
    int iy = min(GRES-1, max(0, (int)((b.y-mny)*ihy)));
    int iz = min(GRES-1, max(0, (int)((b.z-mnz)*ihz)));
    int c = (ix<<10) | (iy<<5) | iz;
    cellid[t] = c;
    atomicAdd(&hist[c], 1u);
}

// ---------------- exclusive prefix over 32768 cells (1 block, 2-level) ----------------
// Thread tid owns cells [tid*32, tid*32+32) via 8 uint4 loads (full-unroll ->
// static register indexing, rule #20), block-scans the 1024 partial sums,
// then writes its 32 exclusive prefixes.
__global__ __launch_bounds__(1024) void prefix_kernel(const unsigned* __restrict__ hist,
                                                      unsigned* __restrict__ cellstart,
                                                      unsigned* __restrict__ cellptr) {
    __shared__ unsigned sbuf[1024];
    int tid = threadIdx.x;
    uint4 v[8];
    unsigned s = 0u;
#pragma unroll
    for (int j = 0; j < 8; ++j) {
        v[j] = ((const uint4*)hist)[tid*8 + j];
        s += v[j].x + v[j].y + v[j].z + v[j].w;
    }
    sbuf[tid] = s;
    __syncthreads();
    for (int off = 1; off < 1024; off <<= 1) {
        unsigned add = (tid >= off) ? sbuf[tid - off] : 0u;
        __syncthreads();
        sbuf[tid] += add;
        __syncthreads();
    }
    unsigned run = sbuf[tid] - s;
#pragma unroll
    for (int j = 0; j < 8; ++j) {
        unsigned p0 = run;
        unsigned p1 = p0 + v[j].x;
        unsigned p2 = p1 + v[j].y;
        unsigned p3 = p2 + v[j].z;
        run = p3 + v[j].w;
        int c = tid*32 + 4*j;
        cellstart[c]   = p0; cellstart[c+1] = p1; cellstart[c+2] = p2; cellstart[c+3] = p3;
        cellptr[c]     = p0; cellptr[c+1]   = p1; cellptr[c+2]   = p2; cellptr[c+3]   = p3;
    }
    if (tid == 1023) cellstart[NCELL] = run;
}

// ---------------- scatter into cell-sorted order (+ relabeled geo/probs) ----------------
// Intra-cell order is atomic-nondeterministic; the selected top-21 set is
// enumeration-order independent (strict lex order on (d, orig idx)), so the
// OUTPUT is deterministic. geo_s/probs_s let the whole layer pipeline run in
// sorted (spatially-local) index space.
__global__ void scatter_kernel(const float4* __restrict__ bq, const int* __restrict__ cellid,
                               const float* __restrict__ geo, const float* __restrict__ probs,
                               unsigned* __restrict__ cellptr, float4* __restrict__ bqs,
                               int* __restrict__ oid, int* __restrict__ csort,
                               float* __restrict__ geo_s, float* __restrict__ probs_s) {
    int t = blockIdx.x * 256 + threadIdx.x;
    if (t >= T_TRI) return;
    int c = cellid[t];
    unsigned p = atomicAdd(&cellptr[c], 1u);
    bqs[p] = bq[t];
    oid[p]  = t;
    csort[p] = c;
    const float4* g4 = (const float4*)geo;
    float4* g4s = (float4*)geo_s;
    g4s[(size_t)p*3+0] = g4[(size_t)t*3+0];
    g4s[(size_t)p*3+1] = g4[(size_t)t*3+1];
    g4s[(size_t)p*3+2] = g4[(size_t)t*3+2];
    probs_s[p] = probs[t];
}

// ---------------- grid KNN (32^3): exact top-21, conservative window pruning ----------------
// One wave per sorted-order query. Stop after window w iff th < (w*hmin-1e-3)^2
// (slack 1e-3 dwarfs the ~1e-6 formula error -> exact; same argument as the
// R11-passing kernel). Distance formula, insert/drain logic, and tie-break on
// ORIGINAL indices are byte-identical to R4..R11. The insert network also
// carries the SORTED index (rk) so nbr is emitted in sorted space.
__global__ __launch_bounds__(256) void knn_grid_kernel(const float4* __restrict__ bqs,
        const int* __restrict__ oid, const int* __restrict__ csort,
        const unsigned* __restrict__ cellstart, const unsigned* __restrict__ mm,
        int* __restrict__ nbr) {
    int wave = threadIdx.x >> 6, lane = threadIdx.x & 63;
    int r = blockIdx.x * 4 + wave;
    float4 q = bqs[r];
    int myc = csort[r];
    int cx = (myc>>10)&31, cy = (myc>>5)&31, cz = myc&31;
    float hx = (decf(mm[3]) - decf(mm[0])) * (1.f/GRES);
    float hy = (decf(mm[4]) - decf(mm[1])) * (1.f/GRES);
    float hz = (decf(mm[5]) - decf(mm[2])) * (1.f/GRES);
    float hmin = fminf(hx, fminf(hy, hz));

    float rd = INFINITY;
    int   ri = 0x7FF00000 | lane;     // distinct sentinels (orig-idx key)
    int   rk = lane;                  // sorted idx payload
    float th = INFINITY;
    int   mi = 0x7FFFFFFF;

    for (int w = 1; w <= GRES-1; ++w) {
        int W = 2*w + 1, W2 = W*W, tot = W*W2;
        for (int b0 = 0; b0 < tot; b0 += 64) {
            int i = b0 + lane;
            bool val = (i < tot);
            int ii = val ? i : 0;
            int dz = ii % W - w, dy = (ii / W) % W - w, dx = ii / W2 - w;
            int cheb = max(abs(dx), max(abs(dy), abs(dz)));
            val = val && ((w == 1) ? (cheb <= 1) : (cheb == w));
            int ex = cx + dx, ey = cy + dy, ez = cz + dz;
            val = val && ex >= 0 && ex < GRES && ey >= 0 && ey < GRES && ez >= 0 && ez < GRES;
            int cell = (ex<<10) | (ey<<5) | ez;
            unsigned cs = 0u, ce = 0u;
            if (val) { cs = cellstart[cell]; ce = cellstart[cell+1]; }
            val = val && (cs < ce);
            unsigned long long cm = __ballot(val);
            while (cm) {
                int cl = __ffsll(cm) - 1;
                cm &= cm - 1;
                unsigned s0 = (unsigned)__builtin_amdgcn_readlane((int)cs, cl);
                unsigned e0 = (unsigned)__builtin_amdgcn_readlane((int)ce, cl);
                for (unsigned base = s0; base < e0; base += 64u) {
                    unsigned k = base + (unsigned)lane;
                    bool kv = (k < e0);
                    float4 c4 = kv ? bqs[k] : make_float4(INFINITY, INFINITY, INFINITY, INFINITY);
                    int ov = kv ? oid[k] : 0x7FFFFFFF;
                    float dot = fmaf(q.z, c4.z, fmaf(q.y, c4.y, q.x*c4.x));
                    float d = (q.w + c4.w) - 2.0f*dot;
                    unsigned long long bal = __ballot(kv && (d <= th));
                    while (bal) {
                        int src = __ffsll(bal) - 1;
                        bal &= bal - 1;
                        float dc = readlane_f(d, src);
                        int   jc = __builtin_amdgcn_readlane(ov, src);
                        int   kc = (int)base + src;
                        if ((dc < th) || (dc == th && jc < mi)) {
                            bool less = (rd < dc) || (rd == dc && ri < jc);
                            int pos = __popcll(__ballot(less) & 0x1FFFFFull);
                            float sd = __shfl_up(rd, 1);
                            int   si = __shfl_up(ri, 1);
                            int   sk = __shfl_up(rk, 1);
                            if (lane < 21) {
                                if (lane == pos)      { rd = dc; ri = jc; rk = kc; }
                                else if (lane > pos)  { rd = sd; ri = si; rk = sk; }
                            }
                            th = readlane_f(rd, 20);
                            mi = __builtin_amdgcn_readlane(ri, 20);
                        }
                    }
                }
            }
        }
        bool covered = (cx-w <= 0) && (cx+w >= GRES-1) && (cy-w <= 0) && (cy+w >= GRES-1)
                    && (cz-w <= 0) && (cz+w >= GRES-1);
        if (covered) break;
        float bd = (float)w * hmin - 1e-3f;
        if (bd > 0.f && th < bd*bd) break;
    }
    // lane l holds rank-l entry; rank 0 = self, dropped; emit SORTED index
    if (lane >= 1 && lane < 21) nbr[r*KNN_K + lane - 1] = rk;
}

// ---------------- layer-0 helpers (sorted space): y0[r][f] = p_s[r]*rowsum ----------------
__global__ void rowsum_kernel(const float* __restrict__ W1, float* __restrict__ rs) {
    int f = threadIdx.x;
    float s = 0.f;
    for (int c = 0; c < H; ++c) s += W1[f*137 + 9 + c];
    rs[f] = s;
}
__global__ void y0_kernel(const float* __restrict__ ps, const float* __restrict__ rs, float* __restrict__ Y) {
    int tid = blockIdx.x * blockDim.x + threadIdx.x;   // over T*H
    int t = tid >> 7, f = tid & 127;
    Y[tid] = ps[t] * rs[f];
}

// ---------------- weight pre-transpose (once, tiny) ----------------
__global__ void wtrans_kernel(const float* __restrict__ W11, const float* __restrict__ W12,
                              const float* __restrict__ W20, const float* __restrict__ W21,
                              const float* __restrict__ W22, float* __restrict__ WTg) {
    int f = threadIdx.x, c = blockIdx.x, m = blockIdx.y;
    const float* W; int stride, col0;
    if      (m == 0) { W = W11; stride = 137; col0 = 9; }
    else if (m == 1) { W = W12; stride = 137; col0 = 9; }
    else if (m == 2) { W = W20; stride = 128; col0 = 0; }
    else if (m == 3) { W = W21; stride = 128; col0 = 0; }
    else             { W = W22; stride = 128; col0 = 0; }
    WTg[m*16384 + (c>>2)*512 + f*4 + (c&3)] = W[f*stride + col0 + c];
}

// ---------------- standalone dense (sorted space): Y_s = X_s@W1b^T ----------------
#define DTPB 16
__global__ __launch_bounds__(128) void dense_kernel(const float* __restrict__ A, const float* __restrict__ WTg,
                             float* __restrict__ C) {
    __shared__ float Ar[8][128];
    int f = threadIdx.x;
    int t0 = blockIdx.x * DTPB;
    for (int tt = 0; tt < DTPB; tt += 8) {
        __syncthreads();
#pragma unroll
        for (int j = 0; j < 8; ++j) Ar[j][f] = A[(size_t)(t0+tt+j)*H + f];
        __syncthreads();
        float a0 = 0.f, a1 = 0.f, a2 = 0.f, a3 = 0.f;
        float a4_ = 0.f, a5 = 0.f, a6 = 0.f, a7 = 0.f;
#pragma unroll
        for (int c4 = 0; c4 < 32; ++c4) {
            float4 w = *(const float4*)&WTg[c4*512 + f*4];
#define DROW(J, ACC)                                                        \
            {                                                               \
                float4 v = ((const float4*)Ar[J])[c4];                      \
                ACC = fmaf(w.x, v.x, ACC); ACC = fmaf(w.y, v.y, ACC);       \
                ACC = fmaf(w.z, v.z, ACC); ACC = fmaf(w.w, v.w, ACC);       \
            }
            DROW(0, a0) DROW(1, a1) DROW(2, a2) DROW(3, a3)
            DROW(4, a4_) DROW(5, a5) DROW(6, a6) DROW(7, a7)
#undef DROW
        }
        C[(size_t)(t0+tt+0)*H + f] = a0;
        C[(size_t)(t0+tt+1)*H + f] = a1;
        C[(size_t)(t0+tt+2)*H + f] = a2;
        C[(size_t)(t0+tt+3)*H + f] = a3;
        C[(size_t)(t0+tt+4)*H + f] = a4_;
        C[(size_t)(t0+tt+5)*H + f] = a5;
        C[(size_t)(t0+tt+6)*H + f] = a6;
        C[(size_t)(t0+tt+7)*H + f] = a7;
    }
}

// ---------------- fused edge + W2 (+ head), sorted space ----------------
// Structure identical to the R10/R11-passing kernel; indices are sorted-space
// (nbr_s targets are spatially local -> Y-gathers hit L1/L2), and only the
// final sigmoid scatters to out[oid[row]]. Per-triangle numerics bit-identical.
__global__ __launch_bounds__(256) void edgefused_kernel(const float* __restrict__ Y, const float* __restrict__ geo_s,
                            const int* __restrict__ nbr, const float* __restrict__ W1,
                            const float* __restrict__ b1, const float* __restrict__ WTg,
                            const float* __restrict__ b2, float* __restrict__ X,
                            const float* __restrict__ Wf, const float* __restrict__ bf,
                            float* __restrict__ out, const int* __restrict__ oid, int last) {
    __shared__ float W1aT[9][128];
    __shared__ float Srow[4][128];
    __shared__ float fpart[4][2];
    for (int idx = threadIdx.x; idx < 9*128; idx += 256) {
        int c = idx >> 7, ff = idx & 127;
        W1aT[c][ff] = W1[ff*137 + c];
    }
    __syncthreads();
    int wave = threadIdx.x >> 6, lane = threadIdx.x & 63;
    int t0b = blockIdx.x * 4;
    {
        int t = t0b + wave;
        float wlo[9], whi[9];
#pragma unroll
        for (int c = 0; c < 9; ++c) { wlo[c] = W1aT[c][lane]; whi[c] = W1aT[c][64+lane]; }
        const float4* g4 = (const float4*)geo_s;
        float4 s0 = g4[t*3+0], s1 = g4[t*3+1], s2 = g4[t*3+2];
        float b1lo = b1[lane],            b1hi = b1[64+lane];
        float ylo  = Y[(size_t)t*H+lane], yhi  = Y[(size_t)t*H+64+lane];
        float accLo = 0.f, accHi = 0.f;
#pragma unroll
        for (int e = 0; e < KNN_K; ++e) {
            int tg = nbr[t*KNN_K + e];
            float4 t0 = g4[tg*3+0], t1 = g4[tg*3+1], t2 = g4[tg*3+2];
            float r0 = s0.x-t0.x, r1 = s0.y-t0.y, r2 = s0.z-t0.z, r3 = s0.w-t0.w;
            float r4 = s1.x-t1.x, r5 = s1.y-t1.y, r6 = s1.z-t1.z, r7 = s1.w-t1.w;
            float r8 = s2.x-t2.x;
            float gLo = b1lo;
            gLo = fmaf(wlo[0], r0, gLo); gLo = fmaf(wlo[1], r1, gLo); gLo = fmaf(wlo[2], r2, gLo);
            gLo = fmaf(wlo[3], r3, gLo); gLo = fmaf(wlo[4], r4, gLo);
            gLo = fmaf(wlo[5], r5, gLo); gLo = fmaf(wlo[6], r6, gLo);
            gLo = fmaf(wlo[7], r7, gLo); gLo = fmaf(wlo[8], r8, gLo);
            float gHi = b1hi;
            gHi = fmaf(whi[0], r0, gHi); gHi = fmaf(whi[1], r1, gHi); gHi = fmaf(whi[2], r2, gHi);
            gHi = fmaf(whi[3], r3, gHi); gHi = fmaf(whi[4], r4, gHi);
            gHi = fmaf(whi[5], r5, gHi); gHi = fmaf(whi[6], r6, gHi);
            gHi = fmaf(whi[7], r7, gHi); gHi = fmaf(whi[8], r8, gHi);
            accLo += fmaxf(gLo + ylo - Y[(size_t)tg*H + lane], 0.f);
            accHi += fmaxf(gHi + yhi - Y[(size_t)tg*H + 64 + lane], 0.f);
        }
        Srow[wave][lane]    = accLo;
        Srow[wave][64+lane] = accHi;
    }
    __syncthreads();
    int f = threadIdx.x & 127, half = threadIdx.x >> 7;
    float base = b2[f] * (float)KNN_K;
    float a0 = base, a1 = base;
    const int r0_ = half * 2;
#pragma unroll
    for (int c4 = 0; c4 < 32; ++c4) {
        float4 w = *(const float4*)&WTg[c4*512 + f*4];
        float4 v0 = ((const float4*)Srow[r0_+0])[c4];
        float4 v1 = ((const float4*)Srow[r0_+1])[c4];
        a0 = fmaf(w.x, v0.x, a0); a0 = fmaf(w.y, v0.y, a0);
        a0 = fmaf(w.z, v0.z, a0); a0 = fmaf(w.w, v0.w, a0);
        a1 = fmaf(w.x, v1.x, a1); a1 = fmaf(w.y, v1.y, a1);
        a1 = fmaf(w.z, v1.z, a1); a1 = fmaf(w.w, v1.w, a1);
    }
    if (!last) {
        X[(size_t)(t0b+r0_+0)*H + f] = a0;
        X[(size_t)(t0b+r0_+1)*H + f] = a1;
    } else {
        float wf = Wf[f];
        float p0 = a0*wf, p1 = a1*wf;
#pragma unroll
        for (int off = 32; off >= 1; off >>= 1) {
            p0 += __shfl_xor(p0, off);
            p1 += __shfl_xor(p1, off);
        }
        if (lane == 0) { fpart[wave][0] = p0; fpart[wave][1] = p1; }
        __syncthreads();
        if (threadIdx.x < 4) {
            int rr = threadIdx.x;
            int h = rr >> 1, j = rr & 1;
            float z = fpart[2*h][j] + fpart[2*h+1][j] + bf[0];
            out[oid[t0b + h*2 + j]] = 1.0f / (1.0f + expf(-z));
        }
    }
}

extern "C" void kernel_launch(void* const* d_in, const int* in_sizes, int n_in,
                              void* d_out, int out_size, void* d_ws, size_t ws_size,
                              hipStream_t stream) {
    (void)in_sizes; (void)n_in; (void)out_size; (void)ws_size;
    const float* pts   = (const float*)d_in[0];
    const int*   tris  = (const int*)d_in[1];
    const float* probs = (const float*)d_in[2];
    const float* W1[3] = {(const float*)d_in[3],  (const float*)d_in[7],  (const float*)d_in[11]};
    const float* b1[3] = {(const float*)d_in[4],  (const float*)d_in[8],  (const float*)d_in[12]};
    const float* W2[3] = {(const float*)d_in[5],  (const float*)d_in[9],  (const float*)d_in[13]};
    const float* b2[3] = {(const float*)d_in[6],  (const float*)d_in[10], (const float*)d_in[14]};
    const float* Wf = (const float*)d_in[15];
    const float* bf = (const float*)d_in[16];
    float* out = (float*)d_out;

    char* ws = (char*)d_ws;
    float*    geo  = (float*)(ws + WS_GEO);
    float4*   bq   = (float4*)(ws + WS_BQ);
    int*      nbr  = (int*)(ws + WS_NBR);
    float*    rs   = (float*)(ws + WS_RS);
    float*    WTg  = (float*)(ws + WS_WT);
    unsigned* mm   = (unsigned*)(ws + WS_MM);
    unsigned* hist = (unsigned*)(ws + WS_HIST);
    unsigned* cst  = (unsigned*)(ws + WS_CSTART);
    unsigned* cptr = (unsigned*)(ws + WS_CPTR);
    int*      cid  = (int*)(ws + WS_CID);
    int*      cso  = (int*)(ws + WS_CSORT);
    int*      oid  = (int*)(ws + WS_OID);
    float4*   bqs  = (float4*)(ws + WS_BQS);
    float*    ps   = (float*)(ws + WS_PS);
    float*    geos = (float*)(ws + WS_GEOS);
    float*    X    = (float*)(ws + WS_X);
    float*    Y    = (float*)(ws + WS_Y);

    grid_init_kernel<<<NCELL/256, 256, 0, stream>>>(hist, mm);
    geom_kernel<<<(T_TRI+255)/256, 256, 0, stream>>>(pts, tris, geo, bq, mm);
    cellhist_kernel<<<(T_TRI+255)/256, 256, 0, stream>>>(bq, mm, cid, hist);
    prefix_kernel<<<1, 1024, 0, stream>>>(hist, cst, cptr);
    scatter_kernel<<<(T_TRI+255)/256, 256, 0, stream>>>(bq, cid, geo, probs, cptr, bqs, oid, cso, geos, ps);
    knn_grid_kernel<<<T_TRI/4, 256, 0, stream>>>(bqs, oid, cso, cst, mm, nbr);
    rowsum_kernel<<<1, 128, 0, stream>>>(W1[0], rs);
    wtrans_kernel<<<dim3(128,5), 128, 0, stream>>>(W1[1], W1[2], W2[0], W2[1], W2[2], WTg);
    y0_kernel<<<(T_TRI*H)/256, 256, 0, stream>>>(ps, rs, Y);
    for (int l = 0; l < 3; ++l) {
        if (l > 0)
            dense_kernel<<<T_TRI/DTPB, 128, 0, stream>>>(X, WTg + (size_t)(l-1)*16384, Y);
        edgefused_kernel<<<T_TRI/4, 256, 0, stream>>>(Y, geos, nbr, W1[l], b1[l],
                                                      WTg + (size_t)(2+l)*16384, b2[l], X,
                                                      Wf, bf, out, oid, (l == 2) ? 1 : 0);
    }
}